// Round 16
// baseline (374.958 us; speedup 1.0000x reference)
//
#include <hip/hip_runtime.h>
#include <hip/hip_bf16.h>
#include <hip/hip_fp16.h>
#include <hip/hip_cooperative_groups.h>

namespace cg = cooperative_groups;

// Problem constants (from reference)
constexpr int E = 10000, R = 200, D = 64, DFF = 256, L = 2, H = 8, B = 8, S = 1024;
constexpr int N = B * S;          // 8192
constexpr int QPQ = 3;

typedef _Float16 h2 __attribute__((ext_vector_type(2)));
typedef __fp16 fp16x2 __attribute__((ext_vector_type(2)));
typedef _Float16 f16x4 __attribute__((ext_vector_type(4)));
typedef _Float16 f16x8 __attribute__((ext_vector_type(8)));
typedef float f32x4 __attribute__((ext_vector_type(4)));
union F4H { float4 f4; h2 h[4]; f16x8 v8; };

__device__ __forceinline__ h2 pack2(float a, float b) {
#if __has_builtin(__builtin_amdgcn_cvt_pkrtz)
    fp16x2 r = __builtin_amdgcn_cvt_pkrtz(a, b);
    return __builtin_bit_cast(h2, r);
#else
    h2 r; r.x = (_Float16)a; r.y = (_Float16)b; return r;
#endif
}
__device__ __forceinline__ f32x4 mfma16(f16x8 a, f16x8 b, f32x4 c) {
    return __builtin_amdgcn_mfma_f32_16x16x32_f16(a, b, c, 0, 0, 0);
}
__device__ __forceinline__ f32x4 mfma16k16(f16x4 a, f16x4 b, f32x4 c) {
    return __builtin_amdgcn_mfma_f32_16x16x16f16(a, b, c, 0, 0, 0);
}

__device__ __forceinline__ float wsum64(float v) {
#pragma unroll
    for (int off = 32; off; off >>= 1) v += __shfl_xor(v, off, 64);
    return v;
}

// ---- MFMA B-fragment regions (f16 units, per layer) ------------------------
constexpr int OFFB_WO   = 0;      // [64][64]:  T=4,  KS=2 ->  4096 f16
constexpr int OFFB_WF1  = 4096;   // [64][256]: T=16, KS=2 -> 16384
constexpr int OFFB_WF2  = 20480;  // [256][64]: T=4,  KS=8 -> 16384
constexpr int OFFB_WQKV = 36864;  // [64][192]: T=12, KS=2 -> 12288
constexpr int BFRAG_PER_LAYER = 49152;
constexpr int BF_THREADS = 12288; // 2 layers x 6144

// ---- front B-frag regions (wbf2, f16 units) --------------------------------
constexpr int OFFB2_W1   = 0;      // [128][64]: T=4, KS=4 ->  8192 f16
constexpr int OFFB2_W2   = 8192;   // [64][64]:  T=4, KS=2 ->  4096
constexpr int OFFB2_PROJ = 12288;  // [256][64]: T=4, KS=8 -> 16384
constexpr int BF2_THREADS = 3584;
constexpr int PREP_THREADS = BF_THREADS + BF2_THREADS;  // 15872

// ---- shared-memory arena offsets (bytes) ------------------------------------
constexpr int SM_BYTES = 38592;

// ================= device stage implementations ==============================

__device__ void prep_dev(int t0, const float* Wo, const float* Wf1,
                         const float* Wf2, const float* Wqkv,
                         const float* W1, const float* W2, const float* projW,
                         _Float16* out, _Float16* out2) {
    if (t0 < BF_THREADS) {
        const int t = t0;
        const int l = t / 6144;
        int u = t - l * 6144;
        const int lane = u & 63;
        const int ar = lane & 15, ag = lane >> 4;
        const float* src; int Nn, t_n, s, off, chunk;
        if (u < 512) {                                   // Wo [64][64]
            chunk = u >> 6; t_n = chunk >> 1; s = chunk & 1;
            src = Wo + l * 4096; Nn = 64; off = OFFB_WO;
        } else if (u < 2560) { u -= 512;                 // Wf1 [64][256]
            chunk = u >> 6; t_n = chunk >> 1; s = chunk & 1;
            src = Wf1 + l * 16384; Nn = 256; off = OFFB_WF1;
        } else if (u < 4608) { u -= 2560;                // Wf2 [256][64]
            chunk = u >> 6; t_n = chunk >> 3; s = chunk & 7;
            src = Wf2 + l * 16384; Nn = 64; off = OFFB_WF2;
        } else { u -= 4608;                              // Wqkv [64][192]
            chunk = u >> 6; t_n = chunk >> 1; s = chunk & 1;
            src = Wqkv + l * 12288; Nn = 192; off = OFFB_WQKV;
        }
        _Float16* dst = out + (size_t)l * BFRAG_PER_LAYER + off + ((size_t)chunk * 64 + lane) * 8;
        const int col = t_n * 16 + ar;
#pragma unroll
        for (int i = 0; i < 8; i++) {
            const int k = s * 32 + ag * 8 + i;
            dst[i] = (_Float16)src[k * Nn + col];
        }
        return;
    }
    const int t = t0 - BF_THREADS;
    if (t >= BF2_THREADS) return;
    const int lane = t & 63;
    const int ar = lane & 15, ag = lane >> 4;
    const float* src; int t_n, s, off, chunk;
    if (t < 1024) {                                  // W1 [128][64], KS=4
        chunk = t >> 6; t_n = chunk >> 2; s = chunk & 3;
        src = W1; off = OFFB2_W1;
    } else if (t < 1536) {                           // W2 [64][64], KS=2
        const int u = t - 1024;
        chunk = u >> 6; t_n = chunk >> 1; s = chunk & 1;
        src = W2; off = OFFB2_W2;
    } else {                                         // projW [256][64], KS=8
        const int u = t - 1536;
        chunk = u >> 6; t_n = chunk >> 3; s = chunk & 7;
        src = projW; off = OFFB2_PROJ;
    }
    _Float16* dst = out2 + off + ((size_t)chunk * 64 + lane) * 8;
    const int col = t_n * 16 + ar;
#pragma unroll
    for (int i = 0; i < 8; i++) {
        const int k = s * 32 + ag * 8 + i;
        dst[i] = (_Float16)src[k * 64 + col];
    }
}

__device__ void front_dev(int bid,
                          const int* head, const int* rel, const int* tail,
                          const int* qt, const int* qv,
                          const float* ent_emb, const float* rel_emb,
                          const _Float16* W1B, const float* b1,
                          const _Float16* W2B, const float* b2,
                          const float* attn_w,
                          const _Float16* projB, const float* projb,
                          const _Float16* qkv0B, const float* bqkv0,
                          float* x, _Float16* qkvh,
                          _Float16 (*qx)[136], _Float16 (*hs)[72], _Float16 (*ps)[72],
                          _Float16 (*tok)[264], _Float16 (*act)[72],
                          int* qts, int* qvs, int* hd, int* rl, int* tl,
                          float* s_lds, float* wsf) {
    const int tid = threadIdx.x, wave = tid >> 6, lane = tid & 63;
    const int n0 = bid * 16;
    const int q0 = n0 * 3;
    const int ar = lane & 15, ag = lane >> 4;

    if (tid < 48) qts[tid] = qt[q0 + tid];
    else if (tid < 96) qvs[tid - 48] = qv[q0 + tid - 48];
    else if (tid < 112) hd[tid - 96] = head[n0 + tid - 96];
    else if (tid < 128) rl[tid - 112] = rel[n0 + tid - 112];
    else if (tid < 144) tl[tid - 128] = tail[n0 + tid - 128];

    f16x8 w1f[4];
#pragma unroll
    for (int s = 0; s < 4; s++)
        w1f[s] = *(const f16x8*)&W1B[((size_t)(wave * 4 + s) * 64 + lane) * 8];
    const int colw = wave * 16 + ar;
    const float bb1 = b1[colw], bb2 = b2[colw];
    __syncthreads();

#pragma unroll
    for (int i = 0; i < 24; i++) {
        const int f = tid + i * 256;
        const int row = f >> 7, col = f & 127;
        const float v = (col < 64) ? rel_emb[qts[row] * D + col]
                                   : ent_emb[(size_t)qvs[row] * D + (col - 64)];
        qx[row][col] = (_Float16)v;
    }
    f16x8 w2f[2];
#pragma unroll
    for (int s = 0; s < 2; s++)
        w2f[s] = *(const f16x8*)&W2B[((size_t)(wave * 2 + s) * 64 + lane) * 8];
    __syncthreads();

    // h = relu(qx @ W1 + b1)
#pragma unroll
    for (int rt = 0; rt < 3; rt++) {
        f32x4 c = {0.f, 0.f, 0.f, 0.f};
#pragma unroll
        for (int s = 0; s < 4; s++) {
            const f16x8 a = *(const f16x8*)&qx[rt * 16 + ar][s * 32 + ag * 8];
            c = mfma16(a, w1f[s], c);
        }
#pragma unroll
        for (int j = 0; j < 4; j++)
            hs[rt * 16 + ag * 4 + j][colw] = (_Float16)fmaxf(c[j] + bb1, 0.f);
    }
    f16x8 pjf[8];
#pragma unroll
    for (int st = 0; st < 8; st++)
        pjf[st] = *(const f16x8*)&projB[((size_t)(wave * 8 + st) * 64 + lane) * 8];
    __syncthreads();

    // p = hs @ W2 + b2
#pragma unroll
    for (int rt = 0; rt < 3; rt++) {
        f32x4 c = {0.f, 0.f, 0.f, 0.f};
#pragma unroll
        for (int s = 0; s < 2; s++) {
            const f16x8 a = *(const f16x8*)&hs[rt * 16 + ar][s * 32 + ag * 8];
            c = mfma16(a, w2f[s], c);
        }
#pragma unroll
        for (int j = 0; j < 4; j++)
            ps[rt * 16 + ag * 4 + j][colw] = (_Float16)(c[j] + bb2);
    }
    __syncthreads();

    // scores
    {
        const float aw = attn_w[lane];
#pragma unroll
        for (int r = 0; r < 12; r++) {
            const int row = wave * 12 + r;
            const float sv = wsum64((float)ps[row][lane] * aw);
            if (lane == 0) s_lds[row] = sv;
        }
    }
    __syncthreads();
    if (tid < 16) {
        const float s0 = s_lds[tid * 3 + 0], s1 = s_lds[tid * 3 + 1], s2 = s_lds[tid * 3 + 2];
        const float mm = fmaxf(s0, fmaxf(s1, s2));
        const float e0 = __expf(s0 - mm), e1 = __expf(s1 - mm), e2 = __expf(s2 - mm);
        const float rd = 1.f / (e0 + e1 + e2);
        wsf[tid * 3 + 0] = e0 * rd; wsf[tid * 3 + 1] = e1 * rd; wsf[tid * 3 + 2] = e2 * rd;
    }
    __syncthreads();

    // token assembly 16 x 256
#pragma unroll
    for (int i = 0; i < 16; i++) {
        const int f = tid + i * 256;
        const int row = f >> 8, col = f & 255;
        float v;
        if (col < 64)       v = ent_emb[(size_t)hd[row] * D + col];
        else if (col < 128) v = rel_emb[rl[row] * D + (col - 64)];
        else if (col < 192) v = ent_emb[(size_t)tl[row] * D + (col - 128)];
        else {
            const int c = col - 192;
            v = wsf[row * 3 + 0] * (float)ps[row * 3 + 0][c] +
                wsf[row * 3 + 1] * (float)ps[row * 3 + 1][c] +
                wsf[row * 3 + 2] * (float)ps[row * 3 + 2][c];
        }
        tok[row][col] = (_Float16)v;
    }
    f16x8 qvf[6];
#pragma unroll
    for (int tt = 0; tt < 3; tt++) {
        const int tn = wave * 3 + tt;
        qvf[2 * tt]     = *(const f16x8*)&qkv0B[((size_t)(tn * 2 + 0) * 64 + lane) * 8];
        qvf[2 * tt + 1] = *(const f16x8*)&qkv0B[((size_t)(tn * 2 + 1) * 64 + lane) * 8];
    }
    __syncthreads();

    // proj (K=256)
    {
        f32x4 c = {0.f, 0.f, 0.f, 0.f};
#pragma unroll
        for (int st = 0; st < 8; st++) {
            const f16x8 a = *(const f16x8*)&tok[ar][st * 32 + ag * 8];
            c = mfma16(a, pjf[st], c);
        }
        const float bb = projb[colw];
#pragma unroll
        for (int j = 0; j < 4; j++) {
            const int row = ag * 4 + j;
            const float xv = c[j] + bb;
            x[(size_t)(n0 + row) * D + colw] = xv;
            act[row][colw] = (_Float16)xv;
        }
    }
    __syncthreads();

    // layer-0 QKV
    {
        const f16x8 a0 = *(const f16x8*)&act[ar][ag * 8];
        const f16x8 a1 = *(const f16x8*)&act[ar][32 + ag * 8];
#pragma unroll
        for (int tt = 0; tt < 3; tt++) {
            const int tn = wave * 3 + tt;
            f32x4 c = {0.f, 0.f, 0.f, 0.f};
            c = mfma16(a0, qvf[2 * tt], c);
            c = mfma16(a1, qvf[2 * tt + 1], c);
            const int col = tn * 16 + ar;
            const float bb = bqkv0[col];
#pragma unroll
            for (int j = 0; j < 4; j++)
                qkvh[(size_t)(n0 + ag * 4 + j) * 192 + col] = (_Float16)(c[j] + bb);
        }
    }
}

// attention: block r handles (b,h) and 2 query-chunks of 64 (staging K/V once)
__device__ void attn_dev(int r, const _Float16* qkvh, _Float16* out,
                         _Float16 (*Kl)[8], _Float16 (*Vt)[1032]) {
    const int qp = r & 7;
    const int h  = (r >> 3) & 7;
    const int b  = r >> 6;
    const int tid = threadIdx.x, wave = tid >> 6, lane = tid & 63;
    const int ar = lane & 15, ag = lane >> 4;

    const _Float16* base = qkvh + (size_t)b * S * 192;
    const _Float16 sch = (_Float16)0.3535533905932738f;
    const h2 sc2 = {sch, sch};
    for (int it = 0; it < 4; it++) {
        const int key = it * 256 + tid;
        F4H u; u.f4 = *(const float4*)(base + (size_t)key * 192 + 64 + h * 8);
#pragma unroll
        for (int i = 0; i < 4; i++) u.h[i] = u.h[i] * sc2;
        *(float4*)&Kl[key][0] = u.f4;
        F4H v; v.f4 = *(const float4*)(base + (size_t)key * 192 + 128 + h * 8);
        const _Float16* vp = (const _Float16*)&v;
#pragma unroll
        for (int d = 0; d < 8; d++) Vt[d][key] = vp[d];
    }
    __syncthreads();

    const int vd = ar & 7;
#pragma unroll
    for (int sub = 0; sub < 2; sub++) {
        const int q0 = (qp * 2 + sub) * 64 + wave * 16;
        f16x4 qf = {};
        if (ag < 2)
            qf = *(const f16x4*)(base + (size_t)(q0 + ar) * 192 + h * 8 + ag * 4);

        f32x4 oacc0 = {0.f, 0.f, 0.f, 0.f}, oacc1 = {0.f, 0.f, 0.f, 0.f};
        float lsum0 = 0.f, lsum1 = 0.f;
        for (int t = 0; t < 64; t += 2) {
#pragma unroll
            for (int uu = 0; uu < 2; uu++) {
                const int k16 = (t + uu) * 16;
                const f16x4 kf = *(const f16x4*)&Kl[k16 + ar][(ag & 1) * 4];
                f32x4 s4 = {0.f, 0.f, 0.f, 0.f};
                s4 = mfma16k16(kf, qf, s4);
                const float p0 = __expf(s4[0]), p1 = __expf(s4[1]);
                const float p2 = __expf(s4[2]), p3 = __expf(s4[3]);
                union { h2 q[2]; f16x4 v; } pu;
                pu.q[0] = pack2(p0, p1); pu.q[1] = pack2(p2, p3);
                const f16x4 vf = *(const f16x4*)&Vt[vd][k16 + ag * 4];
                if (uu == 0) {
                    lsum0 += (p0 + p1) + (p2 + p3);
                    oacc0 = mfma16k16(pu.v, vf, oacc0);
                } else {
                    lsum1 += (p0 + p1) + (p2 + p3);
                    oacc1 = mfma16k16(pu.v, vf, oacc1);
                }
            }
        }
        float lsum = lsum0 + lsum1;
        f32x4 oacc;
#pragma unroll
        for (int j = 0; j < 4; j++) oacc[j] = oacc0[j] + oacc1[j];
        lsum += __shfl_xor(lsum, 16, 64);
        lsum += __shfl_xor(lsum, 32, 64);
        _Float16* op = out + ((size_t)(b * S + q0)) * 64 + h * 8;
#pragma unroll
        for (int j = 0; j < 4; j++) {
            const float lq = __shfl(lsum, 4 * ag + j, 64);
            if (ar < 8)
                op[(size_t)(4 * ag + j) * 64 + ar] = (_Float16)(oacc[j] / lq);
        }
    }
}

// tail: 4 waves, 16-row M-tile, waves split N (round-14 proven form)
__device__ void tail_dev(int bid, float* x, const _Float16* att16,
                         const _Float16* WoB, const float* bo,
                         const float* ln1s, const float* ln1b,
                         const _Float16* Wf1B, const float* bf1,
                         const _Float16* Wf2B, const float* bf2,
                         const float* ln2s, const float* ln2b,
                         const _Float16* WqB, const float* bqkvN,
                         _Float16* qkvh, int do_qkv,
                         float (*xs0)[76], _Float16 (*xs1)[72], _Float16 (*f1s)[264]) {
    const int tid = threadIdx.x, wave = tid >> 6, lane = tid & 63;
    const int n0 = bid * 16;
    const int ar = lane & 15, ag = lane >> 4;
    const int colw = wave * 16 + ar;

    // ---- O-proj + residual -> xs0 (A-frags direct from global)
    {
        const f16x8 a0 = *(const f16x8*)&att16[((size_t)(n0 + ar)) * 64 + ag * 8];
        const f16x8 a1 = *(const f16x8*)&att16[((size_t)(n0 + ar)) * 64 + 32 + ag * 8];
        const f16x8 b0 = *(const f16x8*)&WoB[((size_t)(wave * 2 + 0) * 64 + lane) * 8];
        const f16x8 b1 = *(const f16x8*)&WoB[((size_t)(wave * 2 + 1) * 64 + lane) * 8];
        float res[4];
#pragma unroll
        for (int j = 0; j < 4; j++)
            res[j] = x[(size_t)(n0 + ag * 4 + j) * D + colw];
        f32x4 c = {0.f, 0.f, 0.f, 0.f};
        c = mfma16(a0, b0, c);
        c = mfma16(a1, b1, c);
        const float bb = bo[colw];
#pragma unroll
        for (int j = 0; j < 4; j++)
            xs0[ag * 4 + j][colw] = res[j] + c[j] + bb;
    }
    f16x8 w1f[8];
#pragma unroll
    for (int tt = 0; tt < 4; tt++) {
        const int tn = wave * 4 + tt;
        w1f[2 * tt]     = *(const f16x8*)&Wf1B[((size_t)(tn * 2 + 0) * 64 + lane) * 8];
        w1f[2 * tt + 1] = *(const f16x8*)&Wf1B[((size_t)(tn * 2 + 1) * 64 + lane) * 8];
    }
    __syncthreads();

    // ---- LN1
    {
        const float l1s_ = ln1s[lane], l1b_ = ln1b[lane];
#pragma unroll
        for (int r = 0; r < 4; r++) {
            const int row = wave * 4 + r;
            const float t = xs0[row][lane];
            const float mean = wsum64(t) * (1.f / 64.f);
            const float dv = t - mean;
            const float var = wsum64(dv * dv) * (1.f / 64.f);
            xs1[row][lane] = (_Float16)(dv * rsqrtf(var + 1e-5f) * l1s_ + l1b_);
        }
    }
    f16x8 w2f[8];
#pragma unroll
    for (int s = 0; s < 8; s++)
        w2f[s] = *(const f16x8*)&Wf2B[((size_t)(wave * 8 + s) * 64 + lane) * 8];
    __syncthreads();

    // ---- FFN1 + relu
    {
        const f16x8 a0 = *(const f16x8*)&xs1[ar][ag * 8];
        const f16x8 a1 = *(const f16x8*)&xs1[ar][32 + ag * 8];
#pragma unroll
        for (int tt = 0; tt < 4; tt++) {
            const int tn = wave * 4 + tt;
            f32x4 c = {0.f, 0.f, 0.f, 0.f};
            c = mfma16(a0, w1f[2 * tt], c);
            c = mfma16(a1, w1f[2 * tt + 1], c);
            const int col = tn * 16 + ar;
            const float bb = bf1[col];
#pragma unroll
            for (int j = 0; j < 4; j++)
                f1s[ag * 4 + j][col] = (_Float16)fmaxf(c[j] + bb, 0.f);
        }
    }
    f16x8 qvf[6];
    if (do_qkv) {
#pragma unroll
        for (int tt = 0; tt < 3; tt++) {
            const int tn = wave * 3 + tt;
            qvf[2 * tt]     = *(const f16x8*)&WqB[((size_t)(tn * 2 + 0) * 64 + lane) * 8];
            qvf[2 * tt + 1] = *(const f16x8*)&WqB[((size_t)(tn * 2 + 1) * 64 + lane) * 8];
        }
    }
    __syncthreads();

    // ---- FFN2 (K=256) + residual -> xs0
    {
        f32x4 c = {0.f, 0.f, 0.f, 0.f};
#pragma unroll
        for (int s = 0; s < 8; s++) {
            const f16x8 a = *(const f16x8*)&f1s[ar][s * 32 + ag * 8];
            c = mfma16(a, w2f[s], c);
        }
        const float bb = bf2[colw];
#pragma unroll
        for (int j = 0; j < 4; j++) {
            const int row = ag * 4 + j;
            xs0[row][colw] = (float)xs1[row][colw] + c[j] + bb;
        }
    }
    __syncthreads();

    // ---- LN2 -> x + xs1
    {
        const float l2s_ = ln2s[lane], l2b_ = ln2b[lane];
#pragma unroll
        for (int r = 0; r < 4; r++) {
            const int row = wave * 4 + r;
            const float t = xs0[row][lane];
            const float mean = wsum64(t) * (1.f / 64.f);
            const float dv = t - mean;
            const float var = wsum64(dv * dv) * (1.f / 64.f);
            const float xo = dv * rsqrtf(var + 1e-5f) * l2s_ + l2b_;
            x[(size_t)(n0 + row) * D + lane] = xo;
            xs1[row][lane] = (_Float16)xo;
        }
    }
    if (do_qkv) {
        __syncthreads();
        const f16x8 a0 = *(const f16x8*)&xs1[ar][ag * 8];
        const f16x8 a1 = *(const f16x8*)&xs1[ar][32 + ag * 8];
#pragma unroll
        for (int tt = 0; tt < 3; tt++) {
            const int tn = wave * 3 + tt;
            f32x4 c = {0.f, 0.f, 0.f, 0.f};
            c = mfma16(a0, qvf[2 * tt], c);
            c = mfma16(a1, qvf[2 * tt + 1], c);
            const int col = tn * 16 + ar;
            const float bb = bqkvN[col];
#pragma unroll
            for (int j = 0; j < 4; j++)
                qkvh[(size_t)(n0 + ag * 4 + j) * 192 + col] = (_Float16)(c[j] + bb);
        }
    }
}

// ================= kernel argument bundle =====================================
struct MegaArgs {
    const int *head, *rel, *tail, *qt, *qv;
    const float *ent_emb, *rel_emb;
    const float *mlp_W1, *mlp_b1, *mlp_W2, *mlp_b2, *attn_w;
    const float *proj_W, *proj_b;
    const float *Wqkv, *bqkv, *Wo, *bo, *ln1s, *ln1b, *Wff1, *bff1, *Wff2, *bff2, *ln2s, *ln2b;
    float* x;
    _Float16 *att16, *qkvh, *wbf, *wbf2;
};

// ================= cooperative mega-kernel ====================================
__global__ __launch_bounds__(256, 2)
void mega_kernel(MegaArgs A) {
    __shared__ __align__(16) unsigned char sm[SM_BYTES];
    cg::grid_group grid = cg::this_grid();
    const int bid = blockIdx.x;

    prep_dev(bid * 256 + threadIdx.x, A.Wo, A.Wff1, A.Wff2, A.Wqkv,
             A.mlp_W1, A.mlp_W2, A.proj_W, A.wbf, A.wbf2);
    grid.sync();

    front_dev(bid, A.head, A.rel, A.tail, A.qt, A.qv, A.ent_emb, A.rel_emb,
              A.wbf2 + OFFB2_W1, A.mlp_b1, A.wbf2 + OFFB2_W2, A.mlp_b2, A.attn_w,
              A.wbf2 + OFFB2_PROJ, A.proj_b, A.wbf + OFFB_WQKV, A.bqkv,
              A.x, A.qkvh,
              (_Float16(*)[136])(sm + 0), (_Float16(*)[72])(sm + 13056),
              (_Float16(*)[72])(sm + 19968), (_Float16(*)[264])(sm + 26880),
              (_Float16(*)[72])(sm + 35328),
              (int*)(sm + 37632), (int*)(sm + 37824), (int*)(sm + 38016),
              (int*)(sm + 38080), (int*)(sm + 38144),
              (float*)(sm + 38208), (float*)(sm + 38400));
    grid.sync();

    for (int l = 0; l < L; l++) {
        attn_dev(bid, A.qkvh, A.att16,
                 (_Float16(*)[8])sm, (_Float16(*)[1032])(sm + 16384));
        grid.sync();
        const int nl = (l + 1 < L) ? (l + 1) : 0;
        const _Float16* wb = A.wbf + (size_t)l * BFRAG_PER_LAYER;
        tail_dev(bid, A.x, A.att16,
                 wb + OFFB_WO, A.bo + l * D, A.ln1s + l * D, A.ln1b + l * D,
                 wb + OFFB_WF1, A.bff1 + l * DFF,
                 wb + OFFB_WF2, A.bff2 + l * D,
                 A.ln2s + l * D, A.ln2b + l * D,
                 A.wbf + (size_t)nl * BFRAG_PER_LAYER + OFFB_WQKV, A.bqkv + nl * 3 * D,
                 A.qkvh, (l + 1 < L) ? 1 : 0,
                 (float(*)[76])sm, (_Float16(*)[72])(sm + 4864),
                 (_Float16(*)[264])(sm + 7168));
        if (l + 1 < L) grid.sync();
    }
}

// ================= standalone fallback kernels ================================
__global__ void prep_all_k(const float* Wo, const float* Wf1, const float* Wf2,
                           const float* Wqkv, const float* W1, const float* W2,
                           const float* projW, _Float16* out, _Float16* out2) {
    prep_dev(blockIdx.x * 256 + threadIdx.x, Wo, Wf1, Wf2, Wqkv, W1, W2, projW, out, out2);
}

__global__ __launch_bounds__(256, 2)
void front_k(const int* head, const int* rel, const int* tail,
             const int* qt, const int* qv,
             const float* ent_emb, const float* rel_emb,
             const _Float16* W1B, const float* b1,
             const _Float16* W2B, const float* b2, const float* attn_w,
             const _Float16* projB, const float* projb,
             const _Float16* qkv0B, const float* bqkv0,
             float* x, _Float16* qkvh) {
    __shared__ __align__(16) unsigned char sm[SM_BYTES];
    front_dev(blockIdx.x, head, rel, tail, qt, qv, ent_emb, rel_emb,
              W1B, b1, W2B, b2, attn_w, projB, projb, qkv0B, bqkv0, x, qkvh,
              (_Float16(*)[136])(sm + 0), (_Float16(*)[72])(sm + 13056),
              (_Float16(*)[72])(sm + 19968), (_Float16(*)[264])(sm + 26880),
              (_Float16(*)[72])(sm + 35328),
              (int*)(sm + 37632), (int*)(sm + 37824), (int*)(sm + 38016),
              (int*)(sm + 38080), (int*)(sm + 38144),
              (float*)(sm + 38208), (float*)(sm + 38400));
}

__global__ __launch_bounds__(256, 2)
void attn_k(const _Float16* qkvh, _Float16* out) {
    __shared__ __align__(16) unsigned char sm[33024];
    attn_dev(blockIdx.x, qkvh, out, (_Float16(*)[8])sm, (_Float16(*)[1032])(sm + 16384));
}

__global__ __launch_bounds__(256, 2)
void tail_k(float* x, const _Float16* att16,
            const _Float16* WoB, const float* bo,
            const float* ln1s, const float* ln1b,
            const _Float16* Wf1B, const float* bf1,
            const _Float16* Wf2B, const float* bf2,
            const float* ln2s, const float* ln2b,
            const _Float16* WqB, const float* bqkvN,
            _Float16* qkvh, int do_qkv) {
    __shared__ __align__(16) unsigned char sm[15616];
    tail_dev(blockIdx.x, x, att16, WoB, bo, ln1s, ln1b, Wf1B, bf1, Wf2B, bf2,
             ln2s, ln2b, WqB, bqkvN, qkvh, do_qkv,
             (float(*)[76])sm, (_Float16(*)[72])(sm + 4864), (_Float16(*)[264])(sm + 7168));
}

extern "C" void kernel_launch(void* const* d_in, const int* in_sizes, int n_in,
                              void* d_out, int out_size, void* d_ws, size_t ws_size,
                              hipStream_t stream) {
    MegaArgs A;
    A.head   = (const int*)d_in[0];
    A.rel    = (const int*)d_in[1];
    A.tail   = (const int*)d_in[2];
    A.qt     = (const int*)d_in[3];
    A.qv     = (const int*)d_in[4];
    A.ent_emb = (const float*)d_in[6];
    A.rel_emb = (const float*)d_in[7];
    A.mlp_W1 = (const float*)d_in[8];
    A.mlp_b1 = (const float*)d_in[9];
    A.mlp_W2 = (const float*)d_in[10];
    A.mlp_b2 = (const float*)d_in[11];
    A.attn_w = (const float*)d_in[12];
    A.proj_W = (const float*)d_in[13];
    A.proj_b = (const float*)d_in[14];
    A.Wqkv   = (const float*)d_in[15];
    A.bqkv   = (const float*)d_in[16];
    A.Wo     = (const float*)d_in[17];
    A.bo     = (const float*)d_in[18];
    A.ln1s   = (const float*)d_in[19];
    A.ln1b   = (const float*)d_in[20];
    A.Wff1   = (const float*)d_in[21];
    A.bff1   = (const float*)d_in[22];
    A.Wff2   = (const float*)d_in[23];
    A.bff2   = (const float*)d_in[24];
    A.ln2s   = (const float*)d_in[25];
    A.ln2b   = (const float*)d_in[26];

    A.x     = (float*)d_out;                              // [N, 64]
    A.att16 = (_Float16*)d_ws;                            // N*64
    A.qkvh  = A.att16 + (size_t)N * 64;                   // N*192
    A.wbf   = A.qkvh + (size_t)N * 192;                   // tail B-frags
    A.wbf2  = A.wbf + (size_t)2 * BFRAG_PER_LAYER;        // front B-frags

    void* kargs[] = { (void*)&A };
    hipError_t e = hipLaunchCooperativeKernel((const void*)mega_kernel,
                                              dim3(512), dim3(256), kargs, 0, stream);
    if (e == hipSuccess) return;
    (void)hipGetLastError();   // clear sticky error; fall back to multi-kernel path

    prep_all_k<<<(PREP_THREADS + 255) / 256, 256, 0, stream>>>(
        A.Wo, A.Wff1, A.Wff2, A.Wqkv, A.mlp_W1, A.mlp_W2, A.proj_W, A.wbf, A.wbf2);
    front_k<<<N / 16, 256, 0, stream>>>(A.head, A.rel, A.tail, A.qt, A.qv,
                                        A.ent_emb, A.rel_emb,
                                        A.wbf2 + OFFB2_W1, A.mlp_b1,
                                        A.wbf2 + OFFB2_W2, A.mlp_b2, A.attn_w,
                                        A.wbf2 + OFFB2_PROJ, A.proj_b,
                                        A.wbf + OFFB_WQKV, A.bqkv, A.x, A.qkvh);
    for (int l = 0; l < L; l++) {
        attn_k<<<512, 256, 0, stream>>>(A.qkvh, A.att16);
        const int nl = (l + 1 < L) ? (l + 1) : 0;
        const _Float16* wb = A.wbf + (size_t)l * BFRAG_PER_LAYER;
        tail_k<<<N / 16, 256, 0, stream>>>(
            A.x, A.att16,
            wb + OFFB_WO, A.bo + l * D, A.ln1s + l * D, A.ln1b + l * D,
            wb + OFFB_WF1, A.bff1 + l * DFF,
            wb + OFFB_WF2, A.bff2 + l * D,
            A.ln2s + l * D, A.ln2b + l * D,
            A.wbf + (size_t)nl * BFRAG_PER_LAYER + OFFB_WQKV, A.bqkv + nl * 3 * D,
            A.qkvh, (l + 1 < L) ? 1 : 0);
    }
}

// Round 17
// 118.380 us; speedup vs baseline: 3.1674x; 3.1674x over previous
//
#include <hip/hip_runtime.h>
#include <hip/hip_bf16.h>
#include <hip/hip_fp16.h>

// Problem constants (from reference)
constexpr int E = 10000, R = 200, D = 64, DFF = 256, L = 2, H = 8, B = 8, S = 1024;
constexpr int N = B * S;          // 8192
constexpr int QPQ = 3;
constexpr int QQ = N * QPQ;       // 24576
constexpr int DH = D / H;         // 8

typedef _Float16 h2 __attribute__((ext_vector_type(2)));
typedef __fp16 fp16x2 __attribute__((ext_vector_type(2)));
typedef _Float16 f16x4 __attribute__((ext_vector_type(4)));
typedef _Float16 f16x8 __attribute__((ext_vector_type(8)));
typedef float f32x4 __attribute__((ext_vector_type(4)));
union F4H { float4 f4; h2 h[4]; f16x8 v8; };

__device__ __forceinline__ h2 pack2(float a, float b) {
#if __has_builtin(__builtin_amdgcn_cvt_pkrtz)
    fp16x2 r = __builtin_amdgcn_cvt_pkrtz(a, b);
    return __builtin_bit_cast(h2, r);
#else
    h2 r; r.x = (_Float16)a; r.y = (_Float16)b; return r;
#endif
}
__device__ __forceinline__ f32x4 mfma16(f16x8 a, f16x8 b, f32x4 c) {
    return __builtin_amdgcn_mfma_f32_16x16x32_f16(a, b, c, 0, 0, 0);
}
__device__ __forceinline__ f32x4 mfma16k16(f16x4 a, f16x4 b, f32x4 c) {
    return __builtin_amdgcn_mfma_f32_16x16x16f16(a, b, c, 0, 0, 0);
}

__device__ __forceinline__ float wsum64(float v) {
#pragma unroll
    for (int off = 32; off; off >>= 1) v += __shfl_xor(v, off, 64);
    return v;
}

// ---- MFMA B-fragment regions (f16 units, per layer) ------------------------
constexpr int OFFB_WO   = 0;      // [64][64]:  T=4,  KS=2 ->  4096 f16
constexpr int OFFB_WF1  = 4096;   // [64][256]: T=16, KS=2 -> 16384
constexpr int OFFB_WF2  = 20480;  // [256][64]: T=4,  KS=8 -> 16384
constexpr int OFFB_WQKV = 36864;  // [64][192]: T=12, KS=2 -> 12288
constexpr int BFRAG_PER_LAYER = 49152;
constexpr int BF_THREADS = 12288; // 2 layers x 6144

// ---- front B-frag regions (wbf2, f16 units) --------------------------------
constexpr int OFFB2_W1   = 0;      // [128][64]: T=4, KS=4 ->  8192 f16
constexpr int OFFB2_W2   = 8192;   // [64][64]:  T=4, KS=2 ->  4096
constexpr int OFFB2_PROJ = 12288;  // [256][64]: T=4, KS=8 -> 16384
constexpr int BF2_THREADS = 3584;
constexpr int PREP_THREADS = BF_THREADS + BF2_THREADS;  // 15872

// -------- Kernel 0: pack ALL weights into MFMA B fragments ------------------
__global__ void prep_all(const float* __restrict__ Wo, const float* __restrict__ Wf1,
                         const float* __restrict__ Wf2, const float* __restrict__ Wqkv,
                         const float* __restrict__ W1, const float* __restrict__ W2,
                         const float* __restrict__ projW,
                         _Float16* __restrict__ out, _Float16* __restrict__ out2) {
    const int t0 = blockIdx.x * 256 + threadIdx.x;
    if (t0 < BF_THREADS) {
        const int t = t0;
        const int l = t / 6144;
        int u = t - l * 6144;
        const int lane = u & 63;
        const int ar = lane & 15, ag = lane >> 4;
        const float* src; int Nn, t_n, s, off, chunk;
        if (u < 512) {                                   // Wo [64][64]
            chunk = u >> 6; t_n = chunk >> 1; s = chunk & 1;
            src = Wo + l * 4096; Nn = 64; off = OFFB_WO;
        } else if (u < 2560) { u -= 512;                 // Wf1 [64][256]
            chunk = u >> 6; t_n = chunk >> 1; s = chunk & 1;
            src = Wf1 + l * 16384; Nn = 256; off = OFFB_WF1;
        } else if (u < 4608) { u -= 2560;                // Wf2 [256][64]
            chunk = u >> 6; t_n = chunk >> 3; s = chunk & 7;
            src = Wf2 + l * 16384; Nn = 64; off = OFFB_WF2;
        } else { u -= 4608;                              // Wqkv [64][192]
            chunk = u >> 6; t_n = chunk >> 1; s = chunk & 1;
            src = Wqkv + l * 12288; Nn = 192; off = OFFB_WQKV;
        }
        _Float16* dst = out + (size_t)l * BFRAG_PER_LAYER + off + ((size_t)chunk * 64 + lane) * 8;
        const int col = t_n * 16 + ar;
#pragma unroll
        for (int i = 0; i < 8; i++) {
            const int k = s * 32 + ag * 8 + i;
            dst[i] = (_Float16)src[k * Nn + col];
        }
        return;
    }
    const int t = t0 - BF_THREADS;
    if (t >= BF2_THREADS) return;
    const int lane = t & 63;
    const int ar = lane & 15, ag = lane >> 4;
    const float* src; int t_n, s, off, chunk;
    if (t < 1024) {                                  // W1 [128][64], KS=4
        chunk = t >> 6; t_n = chunk >> 2; s = chunk & 3;
        src = W1; off = OFFB2_W1;
    } else if (t < 1536) {                           // W2 [64][64], KS=2
        const int u = t - 1024;
        chunk = u >> 6; t_n = chunk >> 1; s = chunk & 1;
        src = W2; off = OFFB2_W2;
    } else {                                         // projW [256][64], KS=8
        const int u = t - 1536;
        chunk = u >> 6; t_n = chunk >> 3; s = chunk & 7;
        src = projW; off = OFFB2_PROJ;
    }
    _Float16* dst = out2 + off + ((size_t)chunk * 64 + lane) * 8;
    const int col = t_n * 16 + ar;
#pragma unroll
    for (int i = 0; i < 8; i++) {
        const int k = s * 32 + ag * 8 + i;
        dst[i] = (_Float16)src[k * 64 + col];
    }
}

// ---- Kernel 1: fused front: qual MLP + scores + agg + proj + layer0 QKV ----
// block = 16 quads (48 qualifiers); grid N/16 = 512  (round-14 proven form)
__global__ __launch_bounds__(256, 2)
void front_kernel(const int* __restrict__ head, const int* __restrict__ rel,
                  const int* __restrict__ tail,
                  const int* __restrict__ qt, const int* __restrict__ qv,
                  const float* __restrict__ ent_emb, const float* __restrict__ rel_emb,
                  const _Float16* __restrict__ W1B, const float* __restrict__ b1,
                  const _Float16* __restrict__ W2B, const float* __restrict__ b2,
                  const float* __restrict__ attn_w,
                  const _Float16* __restrict__ projB, const float* __restrict__ projb,
                  const _Float16* __restrict__ qkv0B, const float* __restrict__ bqkv0,
                  float* __restrict__ x, _Float16* __restrict__ qkvh) {
    const int tid = threadIdx.x, wave = tid >> 6, lane = tid & 63;
    const int n0 = blockIdx.x * 16;
    const int q0 = n0 * 3;                 // 48 qualifiers
    const int ar = lane & 15, ag = lane >> 4;

    __shared__ _Float16 qx[48][136];   // qual concat input (pad)
    __shared__ _Float16 hs[48][72];    // relu(h)
    __shared__ _Float16 ps[48][72];    // p
    __shared__ _Float16 tok[16][264];  // token concat input (pad)
    __shared__ _Float16 act[16][72];   // x -> QKV input
    __shared__ int qts[48], qvs[48], hd[16], rl[16], tl[16];
    __shared__ float s_lds[48];
    __shared__ float wsf[16][3];

    if (tid < 48) qts[tid] = qt[q0 + tid];
    else if (tid < 96) qvs[tid - 48] = qv[q0 + tid - 48];
    else if (tid < 112) hd[tid - 96] = head[n0 + tid - 96];
    else if (tid < 128) rl[tid - 112] = rel[n0 + tid - 112];
    else if (tid < 144) tl[tid - 128] = tail[n0 + tid - 128];

    // prefetch W1 B-frags into regs + biases
    f16x8 w1f[4];
#pragma unroll
    for (int s = 0; s < 4; s++)
        w1f[s] = *(const f16x8*)&W1B[((size_t)(wave * 4 + s) * 64 + lane) * 8];
    const int colw = wave * 16 + ar;
    const float bb1 = b1[colw], bb2 = b2[colw];
    __syncthreads();

    // gather 48 x 128 qualifier inputs
#pragma unroll
    for (int i = 0; i < 24; i++) {
        const int f = tid + i * 256;
        const int row = f >> 7, col = f & 127;
        const float v = (col < 64) ? rel_emb[qts[row] * D + col]
                                   : ent_emb[(size_t)qvs[row] * D + (col - 64)];
        qx[row][col] = (_Float16)v;
    }
    // prefetch W2 B-frags during gather
    f16x8 w2f[2];
#pragma unroll
    for (int s = 0; s < 2; s++)
        w2f[s] = *(const f16x8*)&W2B[((size_t)(wave * 2 + s) * 64 + lane) * 8];
    __syncthreads();

    // h = relu(qx @ W1 + b1): 3 row-tiles, K=128 (4 steps)
    {
#pragma unroll
        for (int rt = 0; rt < 3; rt++) {
            f32x4 c = {0.f, 0.f, 0.f, 0.f};
#pragma unroll
            for (int s = 0; s < 4; s++) {
                const f16x8 a = *(const f16x8*)&qx[rt * 16 + ar][s * 32 + ag * 8];
                c = mfma16(a, w1f[s], c);
            }
#pragma unroll
            for (int j = 0; j < 4; j++)
                hs[rt * 16 + ag * 4 + j][colw] = (_Float16)fmaxf(c[j] + bb1, 0.f);
        }
    }
    // prefetch proj B-frags
    f16x8 pjf[8];
#pragma unroll
    for (int st = 0; st < 8; st++)
        pjf[st] = *(const f16x8*)&projB[((size_t)(wave * 8 + st) * 64 + lane) * 8];
    __syncthreads();

    // p = hs @ W2 + b2: K=64 (2 steps)
    {
#pragma unroll
        for (int rt = 0; rt < 3; rt++) {
            f32x4 c = {0.f, 0.f, 0.f, 0.f};
#pragma unroll
            for (int s = 0; s < 2; s++) {
                const f16x8 a = *(const f16x8*)&hs[rt * 16 + ar][s * 32 + ag * 8];
                c = mfma16(a, w2f[s], c);
            }
#pragma unroll
            for (int j = 0; j < 4; j++)
                ps[rt * 16 + ag * 4 + j][colw] = (_Float16)(c[j] + bb2);
        }
    }
    __syncthreads();

    // scores
    {
        const float aw = attn_w[lane];
#pragma unroll
        for (int r = 0; r < 12; r++) {
            const int row = wave * 12 + r;
            const float sv = wsum64((float)ps[row][lane] * aw);
            if (lane == 0) s_lds[row] = sv;
        }
    }
    __syncthreads();
    if (tid < 16) {
        const float s0 = s_lds[tid * 3 + 0], s1 = s_lds[tid * 3 + 1], s2 = s_lds[tid * 3 + 2];
        const float mm = fmaxf(s0, fmaxf(s1, s2));
        const float e0 = __expf(s0 - mm), e1 = __expf(s1 - mm), e2 = __expf(s2 - mm);
        const float rd = 1.f / (e0 + e1 + e2);
        wsf[tid][0] = e0 * rd; wsf[tid][1] = e1 * rd; wsf[tid][2] = e2 * rd;
    }
    __syncthreads();

    // token assembly: 16 x 256
#pragma unroll
    for (int i = 0; i < 16; i++) {
        const int f = tid + i * 256;
        const int row = f >> 8, col = f & 255;
        float v;
        if (col < 64)       v = ent_emb[(size_t)hd[row] * D + col];
        else if (col < 128) v = rel_emb[rl[row] * D + (col - 64)];
        else if (col < 192) v = ent_emb[(size_t)tl[row] * D + (col - 128)];
        else {
            const int c = col - 192;
            v = wsf[row][0] * (float)ps[row * 3 + 0][c] +
                wsf[row][1] * (float)ps[row * 3 + 1][c] +
                wsf[row][2] * (float)ps[row * 3 + 2][c];
        }
        tok[row][col] = (_Float16)v;
    }
    // prefetch layer-0 QKV B-frags
    f16x8 qvf[6];
#pragma unroll
    for (int tt = 0; tt < 3; tt++) {
        const int tn = wave * 3 + tt;
        qvf[2 * tt]     = *(const f16x8*)&qkv0B[((size_t)(tn * 2 + 0) * 64 + lane) * 8];
        qvf[2 * tt + 1] = *(const f16x8*)&qkv0B[((size_t)(tn * 2 + 1) * 64 + lane) * 8];
    }
    __syncthreads();

    // proj: K=256 (8 steps)
    {
        f32x4 c = {0.f, 0.f, 0.f, 0.f};
#pragma unroll
        for (int st = 0; st < 8; st++) {
            const f16x8 a = *(const f16x8*)&tok[ar][st * 32 + ag * 8];
            c = mfma16(a, pjf[st], c);
        }
        const float bb = projb[colw];
#pragma unroll
        for (int j = 0; j < 4; j++) {
            const int row = ag * 4 + j;
            const float xv = c[j] + bb;
            x[(size_t)(n0 + row) * D + colw] = xv;
            act[row][colw] = (_Float16)xv;
        }
    }
    __syncthreads();

    // layer-0 QKV (f16 out)
    {
        const f16x8 a0 = *(const f16x8*)&act[ar][ag * 8];
        const f16x8 a1 = *(const f16x8*)&act[ar][32 + ag * 8];
#pragma unroll
        for (int tt = 0; tt < 3; tt++) {
            const int tn = wave * 3 + tt;
            f32x4 c = {0.f, 0.f, 0.f, 0.f};
            c = mfma16(a0, qvf[2 * tt], c);
            c = mfma16(a1, qvf[2 * tt + 1], c);
            const int col = tn * 16 + ar;
            const float bb = bqkv0[col];
#pragma unroll
            for (int j = 0; j < 4; j++)
                qkvh[(size_t)(n0 + ag * 4 + j) * 192 + col] = (_Float16)(c[j] + bb);
        }
    }
}

// -------- Kernel 2: MFMA flash attention, 2 query-chunks per block ----------
// grid: B*H*(S/128) = 512 blocks of 256; K/V staged ONCE per block
__global__ __launch_bounds__(256, 4)
void attn_kernel(const _Float16* __restrict__ qkvh, _Float16* __restrict__ out) {
    const int bid = blockIdx.x;
    const int qp = bid & 7;             // S/128 = 8
    const int h = (bid >> 3) & 7;
    const int b = bid >> 6;
    const int tid = threadIdx.x, wave = tid >> 6, lane = tid & 63;
    const int ar = lane & 15, ag = lane >> 4;

    constexpr int VP = 1032;            // padded V^T row (f16)
    __shared__ _Float16 Kl[S][8];       // 16 KB (pre-scaled by 1/sqrt(8))
    __shared__ _Float16 Vt[8][VP];      // 16.5 KB (transposed)

    const _Float16* base = qkvh + (size_t)b * S * 192;

    // Q B-frags for both sub-chunks first (overlap staging)
    f16x4 qf[2]; int q0s[2];
#pragma unroll
    for (int sub = 0; sub < 2; sub++) {
        q0s[sub] = (qp * 2 + sub) * 64 + wave * 16;
        f16x4 q = {};
        if (ag < 2)
            q = *(const f16x4*)(base + (size_t)(q0s[sub] + ar) * 192 + h * 8 + ag * 4);
        qf[sub] = q;
    }

    const _Float16 sch = (_Float16)0.3535533905932738f;
    const h2 sc2 = {sch, sch};
    for (int it = 0; it < 4; it++) {
        const int key = it * 256 + tid;
        F4H u; u.f4 = *(const float4*)(base + (size_t)key * 192 + 64 + h * 8);
#pragma unroll
        for (int i = 0; i < 4; i++) u.h[i] = u.h[i] * sc2;
        *(float4*)&Kl[key][0] = u.f4;
        F4H v; v.f4 = *(const float4*)(base + (size_t)key * 192 + 128 + h * 8);
        const _Float16* vp = (const _Float16*)&v;
#pragma unroll
        for (int d = 0; d < 8; d++) Vt[d][key] = vp[d];
    }
    __syncthreads();

    const int vd = ar & 7;
#pragma unroll
    for (int sub = 0; sub < 2; sub++) {
        f32x4 oacc0 = {0.f, 0.f, 0.f, 0.f}, oacc1 = {0.f, 0.f, 0.f, 0.f};
        float lsum0 = 0.f, lsum1 = 0.f;
        for (int t = 0; t < 64; t += 2) {
#pragma unroll
            for (int uu = 0; uu < 2; uu++) {
                const int k16 = (t + uu) * 16;
                const f16x4 kf = *(const f16x4*)&Kl[k16 + ar][(ag & 1) * 4];
                f32x4 s4 = {0.f, 0.f, 0.f, 0.f};
                s4 = mfma16k16(kf, qf[sub], s4);   // D[key=k16+4ag+j][q=ar]
                const float p0 = __expf(s4[0]), p1 = __expf(s4[1]);
                const float p2 = __expf(s4[2]), p3 = __expf(s4[3]);
                union { h2 q[2]; f16x4 v; } pu;
                pu.q[0] = pack2(p0, p1); pu.q[1] = pack2(p2, p3);
                const f16x4 vf = *(const f16x4*)&Vt[vd][k16 + ag * 4];
                if (uu == 0) {
                    lsum0 += (p0 + p1) + (p2 + p3);
                    oacc0 = mfma16k16(pu.v, vf, oacc0);
                } else {
                    lsum1 += (p0 + p1) + (p2 + p3);
                    oacc1 = mfma16k16(pu.v, vf, oacc1);
                }
            }
        }
        float lsum = lsum0 + lsum1;
        f32x4 oacc;
#pragma unroll
        for (int j = 0; j < 4; j++) oacc[j] = oacc0[j] + oacc1[j];
        lsum += __shfl_xor(lsum, 16, 64);
        lsum += __shfl_xor(lsum, 32, 64);
        _Float16* op = out + ((size_t)(b * S + q0s[sub])) * 64 + h * 8;
#pragma unroll
        for (int j = 0; j < 4; j++) {
            const float lq = __shfl(lsum, 4 * ag + j, 64);
            if (ar < 8)
                op[(size_t)(4 * ag + j) * 64 + ar] = (_Float16)(oacc[j] / lq);
        }
    }
}

// -------- Kernel 3: MFMA tail: Oproj+LN1+FFN+LN2[+QKV] (round-14 form) ------
// block = 256 thr / 4 waves, M-tile 16 rows; grid N/16 = 512
__global__ __launch_bounds__(256, 2)
void fused_tail_kernel(float* __restrict__ x, const _Float16* __restrict__ att16,
                       const _Float16* __restrict__ WoB, const float* __restrict__ bo,
                       const float* __restrict__ ln1s, const float* __restrict__ ln1b,
                       const _Float16* __restrict__ Wf1B, const float* __restrict__ bf1,
                       const _Float16* __restrict__ Wf2B, const float* __restrict__ bf2,
                       const float* __restrict__ ln2s, const float* __restrict__ ln2b,
                       const _Float16* __restrict__ WqB, const float* __restrict__ bqkvN,
                       _Float16* __restrict__ qkvh, int do_qkv) {
    const int tid = threadIdx.x, wave = tid >> 6, lane = tid & 63;
    const int n0 = blockIdx.x * 16;
    const int ar = lane & 15, ag = lane >> 4;
    const int colw = wave * 16 + ar;

    __shared__ float    xs0[16][76];   // pre-LN f32 scratch
    __shared__ _Float16 xs1[16][72];   // post-LN1 / QKV input
    __shared__ _Float16 f1s[16][264];  // relu(FFN1)

    // ---- Phase B: O-proj + residual -> xs0 (A-frags direct from global)
    {
        const f16x8 a0 = *(const f16x8*)&att16[((size_t)(n0 + ar)) * 64 + ag * 8];
        const f16x8 a1 = *(const f16x8*)&att16[((size_t)(n0 + ar)) * 64 + 32 + ag * 8];
        const f16x8 b0 = *(const f16x8*)&WoB[((size_t)(wave * 2 + 0) * 64 + lane) * 8];
        const f16x8 b1 = *(const f16x8*)&WoB[((size_t)(wave * 2 + 1) * 64 + lane) * 8];
        float res[4];
#pragma unroll
        for (int j = 0; j < 4; j++)
            res[j] = x[(size_t)(n0 + ag * 4 + j) * D + colw];
        f32x4 c = {0.f, 0.f, 0.f, 0.f};
        c = mfma16(a0, b0, c);
        c = mfma16(a1, b1, c);
        const float bb = bo[colw];
#pragma unroll
        for (int j = 0; j < 4; j++)
            xs0[ag * 4 + j][colw] = res[j] + c[j] + bb;
    }
    // prefetch FFN1 B-frags before barrier
    f16x8 w1f[8];
#pragma unroll
    for (int tt = 0; tt < 4; tt++) {
        const int tn = wave * 4 + tt;
        w1f[2 * tt]     = *(const f16x8*)&Wf1B[((size_t)(tn * 2 + 0) * 64 + lane) * 8];
        w1f[2 * tt + 1] = *(const f16x8*)&Wf1B[((size_t)(tn * 2 + 1) * 64 + lane) * 8];
    }
    __syncthreads();

    // ---- Phase C: LN1
    {
        const float l1s_ = ln1s[lane], l1b_ = ln1b[lane];
#pragma unroll
        for (int r = 0; r < 4; r++) {
            const int row = wave * 4 + r;
            const float t = xs0[row][lane];
            const float mean = wsum64(t) * (1.f / 64.f);
            const float dv = t - mean;
            const float var = wsum64(dv * dv) * (1.f / 64.f);
            xs1[row][lane] = (_Float16)(dv * rsqrtf(var + 1e-5f) * l1s_ + l1b_);
        }
    }
    // prefetch FFN2 B-frags
    f16x8 w2f[8];
#pragma unroll
    for (int s = 0; s < 8; s++)
        w2f[s] = *(const f16x8*)&Wf2B[((size_t)(wave * 8 + s) * 64 + lane) * 8];
    __syncthreads();

    // ---- Phase D: FFN1 + relu
    {
        const f16x8 a0 = *(const f16x8*)&xs1[ar][ag * 8];
        const f16x8 a1 = *(const f16x8*)&xs1[ar][32 + ag * 8];
#pragma unroll
        for (int tt = 0; tt < 4; tt++) {
            const int tn = wave * 4 + tt;
            f32x4 c = {0.f, 0.f, 0.f, 0.f};
            c = mfma16(a0, w1f[2 * tt], c);
            c = mfma16(a1, w1f[2 * tt + 1], c);
            const int col = tn * 16 + ar;
            const float bb = bf1[col];
#pragma unroll
            for (int j = 0; j < 4; j++)
                f1s[ag * 4 + j][col] = (_Float16)fmaxf(c[j] + bb, 0.f);
        }
    }
    // prefetch QKV B-frags
    f16x8 qvf[6];
    if (do_qkv) {
#pragma unroll
        for (int tt = 0; tt < 3; tt++) {
            const int tn = wave * 3 + tt;
            qvf[2 * tt]     = *(const f16x8*)&WqB[((size_t)(tn * 2 + 0) * 64 + lane) * 8];
            qvf[2 * tt + 1] = *(const f16x8*)&WqB[((size_t)(tn * 2 + 1) * 64 + lane) * 8];
        }
    }
    __syncthreads();

    // ---- Phase E: FFN2 (K=256) + residual -> xs0
    {
        f32x4 c = {0.f, 0.f, 0.f, 0.f};
#pragma unroll
        for (int s = 0; s < 8; s++) {
            const f16x8 a = *(const f16x8*)&f1s[ar][s * 32 + ag * 8];
            c = mfma16(a, w2f[s], c);
        }
        const float bb = bf2[colw];
#pragma unroll
        for (int j = 0; j < 4; j++) {
            const int row = ag * 4 + j;
            xs0[row][colw] = (float)xs1[row][colw] + c[j] + bb;
        }
    }
    __syncthreads();

    // ---- Phase F: LN2 -> x + xs1 (QKV input)
    {
        const float l2s_ = ln2s[lane], l2b_ = ln2b[lane];
#pragma unroll
        for (int r = 0; r < 4; r++) {
            const int row = wave * 4 + r;
            const float t = xs0[row][lane];
            const float mean = wsum64(t) * (1.f / 64.f);
            const float dv = t - mean;
            const float var = wsum64(dv * dv) * (1.f / 64.f);
            const float xo = dv * rsqrtf(var + 1e-5f) * l2s_ + l2b_;
            x[(size_t)(n0 + row) * D + lane] = xo;
            xs1[row][lane] = (_Float16)xo;
        }
    }
    if (!do_qkv) return;
    __syncthreads();

    // ---- Phase G: next-layer QKV (f16 out)
    {
        const f16x8 a0 = *(const f16x8*)&xs1[ar][ag * 8];
        const f16x8 a1 = *(const f16x8*)&xs1[ar][32 + ag * 8];
#pragma unroll
        for (int tt = 0; tt < 3; tt++) {
            const int tn = wave * 3 + tt;
            f32x4 c = {0.f, 0.f, 0.f, 0.f};
            c = mfma16(a0, qvf[2 * tt], c);
            c = mfma16(a1, qvf[2 * tt + 1], c);
            const int col = tn * 16 + ar;
            const float bb = bqkvN[col];
#pragma unroll
            for (int j = 0; j < 4; j++)
                qkvh[(size_t)(n0 + ag * 4 + j) * 192 + col] = (_Float16)(c[j] + bb);
        }
    }
}

extern "C" void kernel_launch(void* const* d_in, const int* in_sizes, int n_in,
                              void* d_out, int out_size, void* d_ws, size_t ws_size,
                              hipStream_t stream) {
    const int*   head_idx  = (const int*)d_in[0];
    const int*   rel_idx   = (const int*)d_in[1];
    const int*   tail_idx  = (const int*)d_in[2];
    const int*   qual_type = (const int*)d_in[3];
    const int*   qual_val  = (const int*)d_in[4];
    const float* ent_emb = (const float*)d_in[6];
    const float* rel_emb = (const float*)d_in[7];
    const float* mlp_W1  = (const float*)d_in[8];
    const float* mlp_b1  = (const float*)d_in[9];
    const float* mlp_W2  = (const float*)d_in[10];
    const float* mlp_b2  = (const float*)d_in[11];
    const float* attn_w  = (const float*)d_in[12];
    const float* proj_W  = (const float*)d_in[13];
    const float* proj_b  = (const float*)d_in[14];
    const float* Wqkv    = (const float*)d_in[15];
    const float* bqkv    = (const float*)d_in[16];
    const float* Wo      = (const float*)d_in[17];
    const float* bo      = (const float*)d_in[18];
    const float* ln1_s   = (const float*)d_in[19];
    const float* ln1_b   = (const float*)d_in[20];
    const float* Wff1    = (const float*)d_in[21];
    const float* bff1    = (const float*)d_in[22];
    const float* Wff2    = (const float*)d_in[23];
    const float* bff2    = (const float*)d_in[24];
    const float* ln2_s   = (const float*)d_in[25];
    const float* ln2_b   = (const float*)d_in[26];

    float* x = (float*)d_out;                  // [N, 64]

    // workspace layout (f16 units)
    _Float16* att16 = (_Float16*)d_ws;                  // N*64
    _Float16* qkvh  = att16 + (size_t)N * 64;           // N*192
    _Float16* wbf   = qkvh + (size_t)N * 192;           // tail B-frags
    _Float16* wbf2  = wbf + (size_t)2 * BFRAG_PER_LAYER;// front B-frags

    prep_all<<<(PREP_THREADS + 255) / 256, 256, 0, stream>>>(
        Wo, Wff1, Wff2, Wqkv, mlp_W1, mlp_W2, proj_W, wbf, wbf2);
    front_kernel<<<N / 16, 256, 0, stream>>>(head_idx, rel_idx, tail_idx,
                                             qual_type, qual_val, ent_emb, rel_emb,
                                             wbf2 + OFFB2_W1, mlp_b1,
                                             wbf2 + OFFB2_W2, mlp_b2, attn_w,
                                             wbf2 + OFFB2_PROJ, proj_b,
                                             wbf + OFFB_WQKV, bqkv, x, qkvh);
    for (int l = 0; l < L; l++) {
        attn_kernel<<<B * H * (S / 128), 256, 0, stream>>>(qkvh, att16);
        const int nl = (l + 1 < L) ? (l + 1) : 0;
        const _Float16* wb = wbf + (size_t)l * BFRAG_PER_LAYER;
        fused_tail_kernel<<<N / 16, 256, 0, stream>>>(
            x, att16,
            wb + OFFB_WO, bo + l * D, ln1_s + l * D, ln1_b + l * D,
            wb + OFFB_WF1, bff1 + l * DFF,
            wb + OFFB_WF2, bff2 + l * D,
            ln2_s + l * D, ln2_b + l * D,
            wbf + (size_t)nl * BFRAG_PER_LAYER + OFFB_WQKV, bqkv + nl * 3 * D,
            qkvh, (l + 1 < L) ? 1 : 0);
    }
}

// Round 18
// 79.111 us; speedup vs baseline: 4.7397x; 1.4964x over previous
//
#include <hip/hip_runtime.h>
#include <hip/hip_bf16.h>
#include <hip/hip_fp16.h>

// Problem constants (from reference)
constexpr int E = 10000, R = 200, D = 64, DFF = 256, L = 2, H = 8, B = 8, S = 1024;
constexpr int N = B * S;          // 8192
constexpr int QPQ = 3;
constexpr int QQ = N * QPQ;       // 24576
constexpr int DH = D / H;         // 8

typedef _Float16 h2 __attribute__((ext_vector_type(2)));
typedef __fp16 fp16x2 __attribute__((ext_vector_type(2)));
typedef _Float16 f16x4 __attribute__((ext_vector_type(4)));
typedef _Float16 f16x8 __attribute__((ext_vector_type(8)));
typedef float f32x4 __attribute__((ext_vector_type(4)));
union F4H { float4 f4; h2 h[4]; f16x8 v8; };

__device__ __forceinline__ h2 pack2(float a, float b) {
#if __has_builtin(__builtin_amdgcn_cvt_pkrtz)
    fp16x2 r = __builtin_amdgcn_cvt_pkrtz(a, b);
    return __builtin_bit_cast(h2, r);
#else
    h2 r; r.x = (_Float16)a; r.y = (_Float16)b; return r;
#endif
}
__device__ __forceinline__ f32x4 mfma16(f16x8 a, f16x8 b, f32x4 c) {
    return __builtin_amdgcn_mfma_f32_16x16x32_f16(a, b, c, 0, 0, 0);
}
__device__ __forceinline__ f32x4 mfma16k16(f16x4 a, f16x4 b, f32x4 c) {
    return __builtin_amdgcn_mfma_f32_16x16x16f16(a, b, c, 0, 0, 0);
}

__device__ __forceinline__ float wsum64(float v) {
#pragma unroll
    for (int off = 32; off; off >>= 1) v += __shfl_xor(v, off, 64);
    return v;
}

// ---- MFMA B-fragment regions (f16 units, per layer) ------------------------
constexpr int OFFB_WO   = 0;      // [64][64]:  T=4,  KS=2 ->  4096 f16
constexpr int OFFB_WF1  = 4096;   // [64][256]: T=16, KS=2 -> 16384
constexpr int OFFB_WF2  = 20480;  // [256][64]: T=4,  KS=8 -> 16384
constexpr int OFFB_WQKV = 36864;  // [64][192]: T=12, KS=2 -> 12288
constexpr int BFRAG_PER_LAYER = 49152;
constexpr int BF_THREADS = 12288; // 2 layers x 6144

// ---- front B-frag regions (wbf2, f16 units) --------------------------------
constexpr int OFFB2_W1   = 0;      // [128][64]: T=4, KS=4 ->  8192 f16
constexpr int OFFB2_W2   = 8192;   // [64][64]:  T=4, KS=2 ->  4096
constexpr int OFFB2_PROJ = 12288;  // [256][64]: T=4, KS=8 -> 16384
constexpr int BF2_THREADS = 3584;
constexpr int PREP_THREADS = BF_THREADS + BF2_THREADS;  // 15872

// -------- Kernel 0: pack ALL weights into MFMA B fragments ------------------
__global__ void prep_all(const float* __restrict__ Wo, const float* __restrict__ Wf1,
                         const float* __restrict__ Wf2, const float* __restrict__ Wqkv,
                         const float* __restrict__ W1, const float* __restrict__ W2,
                         const float* __restrict__ projW,
                         _Float16* __restrict__ out, _Float16* __restrict__ out2) {
    const int t0 = blockIdx.x * 256 + threadIdx.x;
    if (t0 < BF_THREADS) {
        const int t = t0;
        const int l = t / 6144;
        int u = t - l * 6144;
        const int lane = u & 63;
        const int ar = lane & 15, ag = lane >> 4;
        const float* src; int Nn, t_n, s, off, chunk;
        if (u < 512) {                                   // Wo [64][64]
            chunk = u >> 6; t_n = chunk >> 1; s = chunk & 1;
            src = Wo + l * 4096; Nn = 64; off = OFFB_WO;
        } else if (u < 2560) { u -= 512;                 // Wf1 [64][256]
            chunk = u >> 6; t_n = chunk >> 1; s = chunk & 1;
            src = Wf1 + l * 16384; Nn = 256; off = OFFB_WF1;
        } else if (u < 4608) { u -= 2560;                // Wf2 [256][64]
            chunk = u >> 6; t_n = chunk >> 3; s = chunk & 7;
            src = Wf2 + l * 16384; Nn = 64; off = OFFB_WF2;
        } else { u -= 4608;                              // Wqkv [64][192]
            chunk = u >> 6; t_n = chunk >> 1; s = chunk & 1;
            src = Wqkv + l * 12288; Nn = 192; off = OFFB_WQKV;
        }
        _Float16* dst = out + (size_t)l * BFRAG_PER_LAYER + off + ((size_t)chunk * 64 + lane) * 8;
        const int col = t_n * 16 + ar;
#pragma unroll
        for (int i = 0; i < 8; i++) {
            const int k = s * 32 + ag * 8 + i;
            dst[i] = (_Float16)src[k * Nn + col];
        }
        return;
    }
    const int t = t0 - BF_THREADS;
    if (t >= BF2_THREADS) return;
    const int lane = t & 63;
    const int ar = lane & 15, ag = lane >> 4;
    const float* src; int t_n, s, off, chunk;
    if (t < 1024) {                                  // W1 [128][64], KS=4
        chunk = t >> 6; t_n = chunk >> 2; s = chunk & 3;
        src = W1; off = OFFB2_W1;
    } else if (t < 1536) {                           // W2 [64][64], KS=2
        const int u = t - 1024;
        chunk = u >> 6; t_n = chunk >> 1; s = chunk & 1;
        src = W2; off = OFFB2_W2;
    } else {                                         // projW [256][64], KS=8
        const int u = t - 1536;
        chunk = u >> 6; t_n = chunk >> 3; s = chunk & 7;
        src = projW; off = OFFB2_PROJ;
    }
    _Float16* dst = out2 + off + ((size_t)chunk * 64 + lane) * 8;
    const int col = t_n * 16 + ar;
#pragma unroll
    for (int i = 0; i < 8; i++) {
        const int k = s * 32 + ag * 8 + i;
        dst[i] = (_Float16)src[k * 64 + col];
    }
}

// ---- Kernel 1: fused front: qual MLP + scores + agg + proj + layer0 QKV ----
// block = 16 quads (48 qualifiers); grid N/16 = 512
__global__ __launch_bounds__(256, 2)
void front_kernel(const int* __restrict__ head, const int* __restrict__ rel,
                  const int* __restrict__ tail,
                  const int* __restrict__ qt, const int* __restrict__ qv,
                  const float* __restrict__ ent_emb, const float* __restrict__ rel_emb,
                  const _Float16* __restrict__ W1B, const float* __restrict__ b1,
                  const _Float16* __restrict__ W2B, const float* __restrict__ b2,
                  const float* __restrict__ attn_w,
                  const _Float16* __restrict__ projB, const float* __restrict__ projb,
                  const _Float16* __restrict__ qkv0B, const float* __restrict__ bqkv0,
                  float* __restrict__ x, _Float16* __restrict__ qkvh) {
    const int tid = threadIdx.x, wave = tid >> 6, lane = tid & 63;
    const int n0 = blockIdx.x * 16;
    const int q0 = n0 * 3;                 // 48 qualifiers
    const int ar = lane & 15, ag = lane >> 4;

    __shared__ _Float16 qx[48][136];   // qual concat input (pad)
    __shared__ _Float16 hs[48][72];    // relu(h)
    __shared__ _Float16 ps[48][72];    // p
    __shared__ _Float16 tok[16][264];  // token concat input (pad)
    __shared__ _Float16 act[16][72];   // x -> QKV input
    __shared__ int qts[48], qvs[48], hd[16], rl[16], tl[16];
    __shared__ float s_lds[48];
    __shared__ float wsf[16][3];

    if (tid < 48) qts[tid] = qt[q0 + tid];
    else if (tid < 96) qvs[tid - 48] = qv[q0 + tid - 48];
    else if (tid < 112) hd[tid - 96] = head[n0 + tid - 96];
    else if (tid < 128) rl[tid - 112] = rel[n0 + tid - 112];
    else if (tid < 144) tl[tid - 128] = tail[n0 + tid - 128];

    // prefetch W1 B-frags into regs (independent of LDS) + biases
    f16x8 w1f[4];
#pragma unroll
    for (int s = 0; s < 4; s++)
        w1f[s] = *(const f16x8*)&W1B[((size_t)(wave * 4 + s) * 64 + lane) * 8];
    const int colw = wave * 16 + ar;
    const float bb1 = b1[colw], bb2 = b2[colw];
    __syncthreads();

    // gather 48 x 128 qualifier inputs
#pragma unroll
    for (int i = 0; i < 24; i++) {
        const int f = tid + i * 256;
        const int row = f >> 7, col = f & 127;
        const float v = (col < 64) ? rel_emb[qts[row] * D + col]
                                   : ent_emb[(size_t)qvs[row] * D + (col - 64)];
        qx[row][col] = (_Float16)v;
    }
    // prefetch W2 B-frags during gather
    f16x8 w2f[2];
#pragma unroll
    for (int s = 0; s < 2; s++)
        w2f[s] = *(const f16x8*)&W2B[((size_t)(wave * 2 + s) * 64 + lane) * 8];
    __syncthreads();

    // h = relu(qx @ W1 + b1): 3 row-tiles, K=128 (4 steps)
    {
#pragma unroll
        for (int rt = 0; rt < 3; rt++) {
            f32x4 c = {0.f, 0.f, 0.f, 0.f};
#pragma unroll
            for (int s = 0; s < 4; s++) {
                const f16x8 a = *(const f16x8*)&qx[rt * 16 + ar][s * 32 + ag * 8];
                c = mfma16(a, w1f[s], c);
            }
#pragma unroll
            for (int j = 0; j < 4; j++)
                hs[rt * 16 + ag * 4 + j][colw] = (_Float16)fmaxf(c[j] + bb1, 0.f);
        }
    }
    // prefetch proj B-frags
    f16x8 pjf[8];
#pragma unroll
    for (int st = 0; st < 8; st++)
        pjf[st] = *(const f16x8*)&projB[((size_t)(wave * 8 + st) * 64 + lane) * 8];
    __syncthreads();

    // p = hs @ W2 + b2: K=64 (2 steps)
    {
#pragma unroll
        for (int rt = 0; rt < 3; rt++) {
            f32x4 c = {0.f, 0.f, 0.f, 0.f};
#pragma unroll
            for (int s = 0; s < 2; s++) {
                const f16x8 a = *(const f16x8*)&hs[rt * 16 + ar][s * 32 + ag * 8];
                c = mfma16(a, w2f[s], c);
            }
#pragma unroll
            for (int j = 0; j < 4; j++)
                ps[rt * 16 + ag * 4 + j][colw] = (_Float16)(c[j] + bb2);
        }
    }
    __syncthreads();

    // scores
    {
        const float aw = attn_w[lane];
#pragma unroll
        for (int r = 0; r < 12; r++) {
            const int row = wave * 12 + r;
            const float sv = wsum64((float)ps[row][lane] * aw);
            if (lane == 0) s_lds[row] = sv;
        }
    }
    __syncthreads();
    if (tid < 16) {
        const float s0 = s_lds[tid * 3 + 0], s1 = s_lds[tid * 3 + 1], s2 = s_lds[tid * 3 + 2];
        const float mm = fmaxf(s0, fmaxf(s1, s2));
        const float e0 = __expf(s0 - mm), e1 = __expf(s1 - mm), e2 = __expf(s2 - mm);
        const float rd = 1.f / (e0 + e1 + e2);
        wsf[tid][0] = e0 * rd; wsf[tid][1] = e1 * rd; wsf[tid][2] = e2 * rd;
    }
    __syncthreads();

    // token assembly: 16 x 256
#pragma unroll
    for (int i = 0; i < 16; i++) {
        const int f = tid + i * 256;
        const int row = f >> 8, col = f & 255;
        float v;
        if (col < 64)       v = ent_emb[(size_t)hd[row] * D + col];
        else if (col < 128) v = rel_emb[rl[row] * D + (col - 64)];
        else if (col < 192) v = ent_emb[(size_t)tl[row] * D + (col - 128)];
        else {
            const int c = col - 192;
            v = wsf[row][0] * (float)ps[row * 3 + 0][c] +
                wsf[row][1] * (float)ps[row * 3 + 1][c] +
                wsf[row][2] * (float)ps[row * 3 + 2][c];
        }
        tok[row][col] = (_Float16)v;
    }
    // prefetch layer-0 QKV B-frags
    f16x8 qvf[6];
#pragma unroll
    for (int tt = 0; tt < 3; tt++) {
        const int tn = wave * 3 + tt;
        qvf[2 * tt]     = *(const f16x8*)&qkv0B[((size_t)(tn * 2 + 0) * 64 + lane) * 8];
        qvf[2 * tt + 1] = *(const f16x8*)&qkv0B[((size_t)(tn * 2 + 1) * 64 + lane) * 8];
    }
    __syncthreads();

    // proj: K=256 (8 steps)
    {
        f32x4 c = {0.f, 0.f, 0.f, 0.f};
#pragma unroll
        for (int st = 0; st < 8; st++) {
            const f16x8 a = *(const f16x8*)&tok[ar][st * 32 + ag * 8];
            c = mfma16(a, pjf[st], c);
        }
        const float bb = projb[colw];
#pragma unroll
        for (int j = 0; j < 4; j++) {
            const int row = ag * 4 + j;
            const float xv = c[j] + bb;
            x[(size_t)(n0 + row) * D + colw] = xv;
            act[row][colw] = (_Float16)xv;
        }
    }
    __syncthreads();

    // layer-0 QKV (f16 out)
    {
        const f16x8 a0 = *(const f16x8*)&act[ar][ag * 8];
        const f16x8 a1 = *(const f16x8*)&act[ar][32 + ag * 8];
#pragma unroll
        for (int tt = 0; tt < 3; tt++) {
            const int tn = wave * 3 + tt;
            f32x4 c = {0.f, 0.f, 0.f, 0.f};
            c = mfma16(a0, qvf[2 * tt], c);
            c = mfma16(a1, qvf[2 * tt + 1], c);
            const int col = tn * 16 + ar;
            const float bb = bqkv0[col];
#pragma unroll
            for (int j = 0; j < 4; j++)
                qkvh[(size_t)(n0 + ag * 4 + j) * 192 + col] = (_Float16)(c[j] + bb);
        }
    }
}

// -------- Kernel 2: MFMA flash attention (16x16x16, no split) ---------------
// grid: B*H*(S/64) = 1024 blocks of 256; wave = 16 queries x all 1024 keys
__global__ __launch_bounds__(256, 4)
void attn_kernel(const _Float16* __restrict__ qkvh, _Float16* __restrict__ out) {
    const int bid = blockIdx.x;
    const int qc = bid & 15;
    const int h = (bid >> 4) & 7;
    const int b = bid >> 7;
    const int tid = threadIdx.x, wave = tid >> 6, lane = tid & 63;
    const int ar = lane & 15, ag = lane >> 4;

    constexpr int VP = 1032;            // padded V^T row (f16)
    __shared__ _Float16 Kl[S][8];       // 16 KB (pre-scaled by 1/sqrt(8))
    __shared__ _Float16 Vt[8][VP];      // 16.5 KB (transposed)

    const _Float16* base = qkvh + (size_t)b * S * 192;

    // Q B-frag first (overlaps staging): col=q=ar, k=d=4*ag+i (ag>=2 -> zero)
    const int q0 = qc * 64 + wave * 16;
    f16x4 qf = {};
    if (ag < 2)
        qf = *(const f16x4*)(base + (size_t)(q0 + ar) * 192 + h * 8 + ag * 4);

    const _Float16 sch = (_Float16)0.3535533905932738f;
    const h2 sc2 = {sch, sch};
    for (int it = 0; it < 4; it++) {
        const int key = it * 256 + tid;
        F4H u; u.f4 = *(const float4*)(base + (size_t)key * 192 + 64 + h * 8);
#pragma unroll
        for (int i = 0; i < 4; i++) u.h[i] = u.h[i] * sc2;
        *(float4*)&Kl[key][0] = u.f4;
        F4H v; v.f4 = *(const float4*)(base + (size_t)key * 192 + 128 + h * 8);
        const _Float16* vp = (const _Float16*)&v;
#pragma unroll
        for (int d = 0; d < 8; d++) Vt[d][key] = vp[d];
    }
    __syncthreads();

    f32x4 oacc0 = {0.f, 0.f, 0.f, 0.f}, oacc1 = {0.f, 0.f, 0.f, 0.f};
    float lsum0 = 0.f, lsum1 = 0.f;
    const int vd = ar & 7;
    for (int t = 0; t < 64; t += 2) {
#pragma unroll
        for (int uu = 0; uu < 2; uu++) {
            const int k16 = (t + uu) * 16;
            const f16x4 kf = *(const f16x4*)&Kl[k16 + ar][(ag & 1) * 4];
            f32x4 s4 = {0.f, 0.f, 0.f, 0.f};
            s4 = mfma16k16(kf, qf, s4);     // D[key=k16+4ag+j][q=ar]
            const float p0 = __expf(s4[0]), p1 = __expf(s4[1]);
            const float p2 = __expf(s4[2]), p3 = __expf(s4[3]);
            union { h2 q[2]; f16x4 v; } pu;
            pu.q[0] = pack2(p0, p1); pu.q[1] = pack2(p2, p3);
            const f16x4 vf = *(const f16x4*)&Vt[vd][k16 + ag * 4];
            if (uu == 0) {
                lsum0 += (p0 + p1) + (p2 + p3);
                oacc0 = mfma16k16(pu.v, vf, oacc0);
            } else {
                lsum1 += (p0 + p1) + (p2 + p3);
                oacc1 = mfma16k16(pu.v, vf, oacc1);
            }
        }
    }
    float lsum = lsum0 + lsum1;
    f32x4 oacc;
#pragma unroll
    for (int j = 0; j < 4; j++) oacc[j] = oacc0[j] + oacc1[j];
    lsum += __shfl_xor(lsum, 16, 64);
    lsum += __shfl_xor(lsum, 32, 64);
    _Float16* op = out + ((size_t)(b * S + q0)) * 64 + h * 8;
#pragma unroll
    for (int j = 0; j < 4; j++) {
        const float lq = __shfl(lsum, 4 * ag + j, 64);
        if (ar < 8)
            op[(size_t)(4 * ag + j) * 64 + ar] = (_Float16)(oacc[j] / lq);
    }
}

// -------- Kernel 3: MFMA tail: Oproj+LN1+FFN+LN2[+QKV] ----------------------
// block = 256 thr / 4 waves, M-tile 16 rows; grid N/16 = 512
__global__ __launch_bounds__(256, 2)
void fused_tail_kernel(float* __restrict__ x, const _Float16* __restrict__ att16,
                       const _Float16* __restrict__ WoB, const float* __restrict__ bo,
                       const float* __restrict__ ln1s, const float* __restrict__ ln1b,
                       const _Float16* __restrict__ Wf1B, const float* __restrict__ bf1,
                       const _Float16* __restrict__ Wf2B, const float* __restrict__ bf2,
                       const float* __restrict__ ln2s, const float* __restrict__ ln2b,
                       const _Float16* __restrict__ WqB, const float* __restrict__ bqkvN,
                       _Float16* __restrict__ qkvh, int do_qkv) {
    const int tid = threadIdx.x, wave = tid >> 6, lane = tid & 63;
    const int n0 = blockIdx.x * 16;
    const int ar = lane & 15, ag = lane >> 4;
    const int colw = wave * 16 + ar;

    __shared__ float    xs0[16][76];   // pre-LN f32 scratch
    __shared__ _Float16 xs1[16][72];   // post-LN1 / QKV input
    __shared__ _Float16 f1s[16][264];  // relu(FFN1)

    // ---- Phase B: O-proj + residual -> xs0 (A-frags direct from global)
    {
        const f16x8 a0 = *(const f16x8*)&att16[((size_t)(n0 + ar)) * 64 + ag * 8];
        const f16x8 a1 = *(const f16x8*)&att16[((size_t)(n0 + ar)) * 64 + 32 + ag * 8];
        const f16x8 b0 = *(const f16x8*)&WoB[((size_t)(wave * 2 + 0) * 64 + lane) * 8];
        const f16x8 b1 = *(const f16x8*)&WoB[((size_t)(wave * 2 + 1) * 64 + lane) * 8];
        float res[4];
#pragma unroll
        for (int j = 0; j < 4; j++)
            res[j] = x[(size_t)(n0 + ag * 4 + j) * D + colw];
        f32x4 c = {0.f, 0.f, 0.f, 0.f};
        c = mfma16(a0, b0, c);
        c = mfma16(a1, b1, c);
        const float bb = bo[colw];
#pragma unroll
        for (int j = 0; j < 4; j++)
            xs0[ag * 4 + j][colw] = res[j] + c[j] + bb;
    }
    // prefetch FFN1 B-frags before barrier
    f16x8 w1f[8];
#pragma unroll
    for (int tt = 0; tt < 4; tt++) {
        const int tn = wave * 4 + tt;
        w1f[2 * tt]     = *(const f16x8*)&Wf1B[((size_t)(tn * 2 + 0) * 64 + lane) * 8];
        w1f[2 * tt + 1] = *(const f16x8*)&Wf1B[((size_t)(tn * 2 + 1) * 64 + lane) * 8];
    }
    __syncthreads();

    // ---- Phase C: LN1
    {
        const float l1s_ = ln1s[lane], l1b_ = ln1b[lane];
#pragma unroll
        for (int r = 0; r < 4; r++) {
            const int row = wave * 4 + r;
            const float t = xs0[row][lane];
            const float mean = wsum64(t) * (1.f / 64.f);
            const float dv = t - mean;
            const float var = wsum64(dv * dv) * (1.f / 64.f);
            xs1[row][lane] = (_Float16)(dv * rsqrtf(var + 1e-5f) * l1s_ + l1b_);
        }
    }
    // prefetch FFN2 B-frags
    f16x8 w2f[8];
#pragma unroll
    for (int s = 0; s < 8; s++)
        w2f[s] = *(const f16x8*)&Wf2B[((size_t)(wave * 8 + s) * 64 + lane) * 8];
    __syncthreads();

    // ---- Phase D: FFN1 + relu
    {
        const f16x8 a0 = *(const f16x8*)&xs1[ar][ag * 8];
        const f16x8 a1 = *(const f16x8*)&xs1[ar][32 + ag * 8];
#pragma unroll
        for (int tt = 0; tt < 4; tt++) {
            const int tn = wave * 4 + tt;
            f32x4 c = {0.f, 0.f, 0.f, 0.f};
            c = mfma16(a0, w1f[2 * tt], c);
            c = mfma16(a1, w1f[2 * tt + 1], c);
            const int col = tn * 16 + ar;
            const float bb = bf1[col];
#pragma unroll
            for (int j = 0; j < 4; j++)
                f1s[ag * 4 + j][col] = (_Float16)fmaxf(c[j] + bb, 0.f);
        }
    }
    // prefetch QKV B-frags
    f16x8 qvf[6];
    if (do_qkv) {
#pragma unroll
        for (int tt = 0; tt < 3; tt++) {
            const int tn = wave * 3 + tt;
            qvf[2 * tt]     = *(const f16x8*)&WqB[((size_t)(tn * 2 + 0) * 64 + lane) * 8];
            qvf[2 * tt + 1] = *(const f16x8*)&WqB[((size_t)(tn * 2 + 1) * 64 + lane) * 8];
        }
    }
    __syncthreads();

    // ---- Phase E: FFN2 (K=256) + residual -> xs0
    {
        f32x4 c = {0.f, 0.f, 0.f, 0.f};
#pragma unroll
        for (int s = 0; s < 8; s++) {
            const f16x8 a = *(const f16x8*)&f1s[ar][s * 32 + ag * 8];
            c = mfma16(a, w2f[s], c);
        }
        const float bb = bf2[colw];
#pragma unroll
        for (int j = 0; j < 4; j++) {
            const int row = ag * 4 + j;
            xs0[row][colw] = (float)xs1[row][colw] + c[j] + bb;
        }
    }
    __syncthreads();

    // ---- Phase F: LN2 -> x + xs1 (QKV input)
    {
        const float l2s_ = ln2s[lane], l2b_ = ln2b[lane];
#pragma unroll
        for (int r = 0; r < 4; r++) {
            const int row = wave * 4 + r;
            const float t = xs0[row][lane];
            const float mean = wsum64(t) * (1.f / 64.f);
            const float dv = t - mean;
            const float var = wsum64(dv * dv) * (1.f / 64.f);
            const float xo = dv * rsqrtf(var + 1e-5f) * l2s_ + l2b_;
            x[(size_t)(n0 + row) * D + lane] = xo;
            xs1[row][lane] = (_Float16)xo;
        }
    }
    if (!do_qkv) return;
    __syncthreads();

    // ---- Phase G: next-layer QKV (f16 out)
    {
        const f16x8 a0 = *(const f16x8*)&xs1[ar][ag * 8];
        const f16x8 a1 = *(const f16x8*)&xs1[ar][32 + ag * 8];
#pragma unroll
        for (int tt = 0; tt < 3; tt++) {
            const int tn = wave * 3 + tt;
            f32x4 c = {0.f, 0.f, 0.f, 0.f};
            c = mfma16(a0, qvf[2 * tt], c);
            c = mfma16(a1, qvf[2 * tt + 1], c);
            const int col = tn * 16 + ar;
            const float bb = bqkvN[col];
#pragma unroll
            for (int j = 0; j < 4; j++)
                qkvh[(size_t)(n0 + ag * 4 + j) * 192 + col] = (_Float16)(c[j] + bb);
        }
    }
}

extern "C" void kernel_launch(void* const* d_in, const int* in_sizes, int n_in,
                              void* d_out, int out_size, void* d_ws, size_t ws_size,
                              hipStream_t stream) {
    const int*   head_idx  = (const int*)d_in[0];
    const int*   rel_idx   = (const int*)d_in[1];
    const int*   tail_idx  = (const int*)d_in[2];
    const int*   qual_type = (const int*)d_in[3];
    const int*   qual_val  = (const int*)d_in[4];
    const float* ent_emb = (const float*)d_in[6];
    const float* rel_emb = (const float*)d_in[7];
    const float* mlp_W1  = (const float*)d_in[8];
    const float* mlp_b1  = (const float*)d_in[9];
    const float* mlp_W2  = (const float*)d_in[10];
    const float* mlp_b2  = (const float*)d_in[11];
    const float* attn_w  = (const float*)d_in[12];
    const float* proj_W  = (const float*)d_in[13];
    const float* proj_b  = (const float*)d_in[14];
    const float* Wqkv    = (const float*)d_in[15];
    const float* bqkv    = (const float*)d_in[16];
    const float* Wo      = (const float*)d_in[17];
    const float* bo      = (const float*)d_in[18];
    const float* ln1_s   = (const float*)d_in[19];
    const float* ln1_b   = (const float*)d_in[20];
    const float* Wff1    = (const float*)d_in[21];
    const float* bff1    = (const float*)d_in[22];
    const float* Wff2    = (const float*)d_in[23];
    const float* bff2    = (const float*)d_in[24];
    const float* ln2_s   = (const float*)d_in[25];
    const float* ln2_b   = (const float*)d_in[26];

    float* x = (float*)d_out;                  // [N, 64]

    // workspace layout (f16 units)
    _Float16* att16 = (_Float16*)d_ws;                  // N*64
    _Float16* qkvh  = att16 + (size_t)N * 64;           // N*192
    _Float16* wbf   = qkvh + (size_t)N * 192;           // tail B-frags
    _Float16* wbf2  = wbf + (size_t)2 * BFRAG_PER_LAYER;// front B-frags

    prep_all<<<(PREP_THREADS + 255) / 256, 256, 0, stream>>>(
        Wo, Wff1, Wff2, Wqkv, mlp_W1, mlp_W2, proj_W, wbf, wbf2);
    front_kernel<<<N / 16, 256, 0, stream>>>(head_idx, rel_idx, tail_idx,
                                             qual_type, qual_val, ent_emb, rel_emb,
                                             wbf2 + OFFB2_W1, mlp_b1,
                                             wbf2 + OFFB2_W2, mlp_b2, attn_w,
                                             wbf2 + OFFB2_PROJ, proj_b,
                                             wbf + OFFB_WQKV, bqkv, x, qkvh);
    for (int l = 0; l < L; l++) {
        attn_kernel<<<B * H * (S / 64), 256, 0, stream>>>(qkvh, att16);
        const int nl = (l + 1 < L) ? (l + 1) : 0;
        const _Float16* wb = wbf + (size_t)l * BFRAG_PER_LAYER;
        fused_tail_kernel<<<N / 16, 256, 0, stream>>>(
            x, att16,
            wb + OFFB_WO, bo + l * D, ln1_s + l * D, ln1_b + l * D,
            wb + OFFB_WF1, bff1 + l * DFF,
            wb + OFFB_WF2, bff2 + l * D,
            ln2_s + l * D, ln2_b + l * D,
            wbf + (size_t)nl * BFRAG_PER_LAYER + OFFB_WQKV, bqkv + nl * 3 * D,
            qkvh, (l + 1 < L) ? 1 : 0);
    }
}